// Round 17
// baseline (81.609 us; speedup 1.0000x reference)
//
#include <hip/hip_runtime.h>
#include <hip/hip_bf16.h>

typedef __bf16 bf16;
typedef __bf16 bf16x8 __attribute__((ext_vector_type(8)));
typedef float f32x4 __attribute__((ext_vector_type(4)));
typedef float f32x16 __attribute__((ext_vector_type(16)));
typedef unsigned int u32x4 __attribute__((ext_vector_type(4)));

#define EXP2(x) __builtin_amdgcn_exp2f(x)

static __device__ __forceinline__ f32x4 mfma16(bf16x8 a, bf16x8 b, f32x4 c) {
    return __builtin_amdgcn_mfma_f32_16x16x32_bf16(a, b, c, 0, 0, 0);
}
static __device__ __forceinline__ f32x16 mfma32(bf16x8 a, bf16x8 b, f32x16 c) {
    return __builtin_amdgcn_mfma_f32_32x32x16_bf16(a, b, c, 0, 0, 0);
}
static __device__ __forceinline__ unsigned cvt_pk(float lo, float hi) {
    unsigned r;
    asm("v_cvt_pk_bf16_f32 %0, %1, %2" : "=v"(r) : "v"(lo), "v"(hi));
    return r;
}
static __device__ __forceinline__ void perm32swap(unsigned &a, unsigned &b) {
    asm("v_permlane32_swap_b32 %0, %1" : "+v"(a), "+v"(b));
}

// ---------------- Kernel 1: fused weight-convert + x transpose -------------------------
__global__ __launch_bounds__(256) void prep_kernel(const float* __restrict__ x,
                                                   const float* __restrict__ qkv_w,
                                                   const float* __restrict__ proj_w,
                                                   bf16* __restrict__ xT,
                                                   bf16* __restrict__ wqkv,
                                                   bf16* __restrict__ Wp) {
    __shared__ float tile[64][68];
    int bid = blockIdx.x, t = threadIdx.x;
    if (bid < 512) {
        int nb = (bid & 63) * 64, cb = ((bid >> 6) & 3) * 64, b = bid >> 8;
        int j = t & 15, rc = t >> 4;
        const float* src = x + ((size_t)b * 256 + cb) * 4096 + nb;
#pragma unroll
        for (int i = 0; i < 4; i++) {
            f32x4 v = *(const f32x4*)(src + (size_t)(rc + i * 16) * 4096 + j * 4);
            *(f32x4*)&tile[rc + i * 16][j * 4] = v;
        }
        __syncthreads();
        int n = t >> 2;
        bf16* dst = xT + ((size_t)b * 4096 + nb + n) * 256 + cb;
#pragma unroll
        for (int i = 0; i < 2; i++) {
            int c0 = ((t & 3) + i * 4) * 8;
            bf16x8 v;
#pragma unroll
            for (int jj = 0; jj < 8; jj++) v[jj] = (bf16)tile[c0 + jj][n];
            *(bf16x8*)(dst + c0) = v;
        }
    } else {
        int idx = (bid - 512) * 256 + t;
        const float QSCALE = 0.17677669529663689f * 1.4426950408889634f; // hd^-0.5*log2e
        if (idx < 768 * 256) {
            float v = qkv_w[idx];
            if (idx < 256 * 256) v *= QSCALE;
            wqkv[idx] = (bf16)v;
        } else {
            int j = idx - 768 * 256;
            int o = j >> 8, c = j & 255;
            int ot = o >> 5, l31 = o & 31;
            int kc = c >> 4, hi = (c >> 3) & 1, jj = c & 7;
            Wp[(size_t)(((ot * 16 + kc) * 64 + hi * 32 + l31) * 8 + jj)] = (bf16)proj_w[j];
        }
    }
}

// ---------------- Kernel 2: QKV GEMM, 128x128 tile -------------------------------------
__global__ __launch_bounds__(256) void qkv_gemm_kernel(const bf16* __restrict__ xT,
                                                       const bf16* __restrict__ w,
                                                       bf16* __restrict__ Q,
                                                       bf16* __restrict__ Kp,
                                                       bf16* __restrict__ Vp) {
    int b = blockIdx.z;
    int nb = blockIdx.x * 128, ob = blockIdx.y * 128;
    int t = threadIdx.x, wid = t >> 6, lane = t & 63;
    int l15 = lane & 15, g = lane >> 4;
    int wr = wid >> 1, wc = wid & 1;
    const bf16* xrow = xT + ((size_t)b * 4096 + nb + wr * 64 + l15) * 256 + g * 8;
    const bf16* wrow = w + (size_t)(ob + wc * 64 + l15) * 256 + g * 8;
    f32x4 acc[4][4] = {};
    for (int k0 = 0; k0 < 256; k0 += 32) {
        bf16x8 a[4], bb[4];
#pragma unroll
        for (int rt = 0; rt < 4; rt++) a[rt] = *(const bf16x8*)(xrow + rt * 16 * 256 + k0);
#pragma unroll
        for (int cg = 0; cg < 4; cg++) bb[cg] = *(const bf16x8*)(wrow + cg * 16 * 256 + k0);
#pragma unroll
        for (int rt = 0; rt < 4; rt++)
#pragma unroll
            for (int cg = 0; cg < 4; cg++)
                acc[rt][cg] = mfma16(a[rt], bb[cg], acc[rt][cg]);
    }
#pragma unroll
    for (int rt = 0; rt < 4; rt++) {
#pragma unroll
        for (int cg = 0; cg < 4; cg++) {
            int o = ob + wc * 64 + cg * 16 + l15;
            int tsel = o >> 8;           // 0=Q 1=K 2=V
            int h = (o >> 5) & 7;
            int d = o & 31;
            int n0 = nb + wr * 64 + rt * 16 + g * 4;
            size_t bhbase = ((size_t)b * 8 + h) * 131072;
            if (tsel == 0) {
#pragma unroll
                for (int i = 0; i < 4; i++)
                    Q[(((size_t)b * 8 + h) * 4096 + n0 + i) * 32 + d] = (bf16)acc[rt][cg][i];
            } else if (tsel == 1) {
                int kt = n0 >> 5;
                int which = d >> 4, hi2 = (d >> 3) & 1, j = d & 7;
                size_t base = bhbase + (size_t)(((kt * 2 + which) * 64 + hi2 * 32) * 8 + j);
#pragma unroll
                for (int i = 0; i < 4; i++) {
                    int r5 = (n0 + i) & 31;
                    Kp[base + r5 * 8] = (bf16)acc[rt][cg][i];
                }
            } else {
                int kt = n0 >> 5, kk0 = n0 & 31;
                int which = kk0 >> 4, hi2 = (kk0 >> 3) & 1, j0 = kk0 & 7;
                unsigned p0 = cvt_pk(acc[rt][cg][0], acc[rt][cg][1]);
                unsigned p1 = cvt_pk(acc[rt][cg][2], acc[rt][cg][3]);
                uint2 wv; wv.x = p0; wv.y = p1;
                *(uint2*)(Vp + bhbase + (size_t)(((kt * 2 + which) * 64 + hi2 * 32 + d) * 8 + j0)) = wv;
            }
        }
    }
}

// ---------------- Kernel 3: flash attention (R15-proven, verbatim) --------------------
// Grid 1024 (XCD-swizzled: bh=(w&7)+8*((w>>3)&1), qblk=w>>4, 64 q per block).
// 512 thr = 8 waves, wave = rotated k-octant. Each wave: TWO 32-q tiles sharing
// every K/V fragment load, 512 k, 16 iters, KVBLK=32, loads base+lane*16B.
// Stage-interleaved A/B; VALU row-sum (ones-MFMA failed correctness twice in the
// multi-accumulator structure -- permanently abandoned).
#define PACK(stv, B, OUT) {                                  \
    unsigned _x01 = cvt_pk(stv[B + 0], stv[B + 1]);          \
    unsigned _x23 = cvt_pk(stv[B + 2], stv[B + 3]);          \
    unsigned _y01 = cvt_pk(stv[B + 4], stv[B + 5]);          \
    unsigned _y23 = cvt_pk(stv[B + 6], stv[B + 7]);          \
    perm32swap(_x01, _y01);                                  \
    perm32swap(_x23, _y23);                                  \
    u32x4 _w = {_x01, _x23, _y01, _y23};                     \
    OUT = __builtin_bit_cast(bf16x8, _w); }

__global__ __launch_bounds__(512, 4) void attn_kernel(const bf16* __restrict__ Q,
                                                      const bf16* __restrict__ Kp,
                                                      const bf16* __restrict__ Vp,
                                                      bf16* __restrict__ attP) {
    __shared__ __align__(16) float ldsO[7][2][64][20];   // ~70 KB
    __shared__ float ldsL[7][2][32];

    const int w = blockIdx.x;
    const int bh = (w & 7) + 8 * ((w >> 3) & 1);
    const int qblk = w >> 4;                        // 0..63
    const int t = threadIdx.x;
    const int zraw = t >> 6, lane = t & 63;         // zraw: octant slot 0..7
    const int z = (zraw + qblk) & 7;                // rotated k-octant
    const int l31 = lane & 31, hi = lane >> 5;
    const int q0 = qblk * 64;

    const bf16* __restrict__ Qb = Q + (size_t)bh * 131072;
    const bf16* kp = Kp + (size_t)bh * 131072 + (size_t)z * 16384 + lane * 8;
    const bf16* vp = Vp + (size_t)bh * 131072 + (size_t)z * 16384 + lane * 8;

    bf16x8 qfA0 = *(const bf16x8*)(Qb + (size_t)(q0 + l31) * 32 + hi * 8);
    bf16x8 qfA1 = *(const bf16x8*)(Qb + (size_t)(q0 + l31) * 32 + 16 + hi * 8);
    bf16x8 qfB0 = *(const bf16x8*)(Qb + (size_t)(q0 + 32 + l31) * 32 + hi * 8);
    bf16x8 qfB1 = *(const bf16x8*)(Qb + (size_t)(q0 + 32 + l31) * 32 + 16 + hi * 8);

    const f32x16 ZERO16 = {};
    f32x16 oA = {}, oB = {};
    float lpA = 0.f, lpB = 0.f;

    // prefetch iter 0
    bf16x8 kf0 = *(const bf16x8*)(kp);
    bf16x8 kf1 = *(const bf16x8*)(kp + 512);
    bf16x8 vf0 = *(const bf16x8*)(vp);
    bf16x8 vf1 = *(const bf16x8*)(vp + 512);

    for (int it = 0; it < 16; ++it) {
        // prefetch iter it+1 (tail overrun reads adjacent ws buffer: harmless)
        kp += 1024; vp += 1024;
        bf16x8 kn0 = *(const bf16x8*)(kp);
        bf16x8 kn1 = *(const bf16x8*)(kp + 512);
        bf16x8 vn0 = *(const bf16x8*)(vp);
        bf16x8 vn1 = *(const bf16x8*)(vp + 512);

        // stage 1: both QK^T
        f32x16 stA = mfma32(kf0, qfA0, ZERO16);
        f32x16 stB = mfma32(kf0, qfB0, ZERO16);
        stA = mfma32(kf1, qfA1, stA);
        stB = mfma32(kf1, qfB1, stB);

        // stage 2: both exp blocks
#pragma unroll
        for (int r = 0; r < 16; r++) stA[r] = EXP2(stA[r]);
#pragma unroll
        for (int r = 0; r < 16; r++) stB[r] = EXP2(stB[r]);

        // stage 3: both row-sums
        {
            float a0 = 0.f, a1 = 0.f, b0 = 0.f, b1 = 0.f;
#pragma unroll
            for (int r = 0; r < 8; r++) {
                a0 += stA[r]; a1 += stA[r + 8];
                b0 += stB[r]; b1 += stB[r + 8];
            }
            lpA += a0 + a1;
            lpB += b0 + b1;
        }

        // stage 4: both packs
        bf16x8 pbA0, pbA1, pbB0, pbB1;
        PACK(stA, 0, pbA0);
        PACK(stB, 0, pbB0);
        PACK(stA, 8, pbA1);
        PACK(stB, 8, pbB1);

        // stage 5: both PV accumulations
        oA = mfma32(vf0, pbA0, oA);
        oB = mfma32(vf0, pbB0, oB);
        oA = mfma32(vf1, pbA1, oA);
        oB = mfma32(vf1, pbB1, oB);

        kf0 = kn0; kf1 = kn1; vf0 = vn0; vf1 = vn1;
    }

    lpA += __shfl_xor(lpA, 32);
    lpB += __shfl_xor(lpB, 32);

    // ---- combine 8 k-octant partials via LDS, write attP packed ----
    if (zraw != 0) {
#pragma unroll
        for (int g = 0; g < 4; g++) {
            *(f32x4*)&ldsO[zraw - 1][0][lane][4 * g] =
                f32x4{oA[4 * g + 0], oA[4 * g + 1], oA[4 * g + 2], oA[4 * g + 3]};
            *(f32x4*)&ldsO[zraw - 1][1][lane][4 * g] =
                f32x4{oB[4 * g + 0], oB[4 * g + 1], oB[4 * g + 2], oB[4 * g + 3]};
        }
        if (hi == 0) { ldsL[zraw - 1][0][l31] = lpA; ldsL[zraw - 1][1][l31] = lpB; }
    }
    __syncthreads();
    if (zraw == 0) {
        const int b = bh >> 3, h = bh & 7;
#pragma unroll
        for (int qg = 0; qg < 2; qg++) {
            const f32x16& oo = qg ? oB : oA;
            float lsum = qg ? lpB : lpA;
#pragma unroll
            for (int s = 0; s < 7; s++) lsum += ldsL[s][qg][l31];
            float inv = __builtin_amdgcn_rcpf(lsum);
            int nt = qblk * 2 + qg;
            size_t base = (((size_t)b * 128 + nt) * 16) * 512;
#pragma unroll
            for (int g = 0; g < 4; g++) {
                float e0 = oo[4 * g + 0], e1 = oo[4 * g + 1];
                float e2 = oo[4 * g + 2], e3 = oo[4 * g + 3];
#pragma unroll
                for (int s = 0; s < 7; s++) {
                    f32x4 p = *(const f32x4*)&ldsO[s][qg][lane][4 * g];
                    e0 += p[0]; e1 += p[1]; e2 += p[2]; e3 += p[3];
                }
                e0 *= inv; e1 *= inv; e2 *= inv; e3 *= inv;
                size_t addr = base + (size_t)(((h * 2 + (g >> 1)) * 64 + (g & 1) * 32 + l31) * 8 + 4 * hi);
                uint2 wv;
                wv.x = cvt_pk(e0, e1);
                wv.y = cvt_pk(e2, e3);
                *(uint2*)(attP + addr) = wv;
            }
        }
    }
}

// ---------------- Kernel 4: proj GEMM, fragment-packed --------------------------------
__global__ __launch_bounds__(256) void proj_gemm_kernel(const bf16* __restrict__ attP,
                                                        const bf16* __restrict__ Wp,
                                                        const float* __restrict__ bias,
                                                        float* __restrict__ out) {
    int bid = blockIdx.x;
    int b = bid >> 8, rest = bid & 255;
    int nt = rest >> 1, oh = rest & 1;
    int t = threadIdx.x, wid = t >> 6, lane = t & 63;
    int l31 = lane & 31, hi = lane >> 5;
    int ot = oh * 4 + wid;

    const bf16* ap = Wp + (size_t)(ot * 16) * 512 + lane * 8;
    const bf16* bp = attP + (((size_t)b * 128 + nt) * 16) * 512 + lane * 8;
    f32x16 acc = {};
#pragma unroll
    for (int kc = 0; kc < 16; kc++) {
        bf16x8 af = *(const bf16x8*)(ap + kc * 512);
        bf16x8 bf = *(const bf16x8*)(bp + kc * 512);
        acc = mfma32(af, bf, acc);
    }
    float* obase = out + ((size_t)b * 256 + ot * 32) * 4096 + nt * 32 + l31;
#pragma unroll
    for (int r = 0; r < 16; r++) {
        int row = (r & 3) + 8 * (r >> 2) + 4 * hi;
        obase[(size_t)row * 4096] = acc[r] + bias[ot * 32 + row];
    }
}

// ---------------- launch --------------------------------------------------------------
extern "C" void kernel_launch(void* const* d_in, const int* in_sizes, int n_in,
                              void* d_out, int out_size, void* d_ws, size_t ws_size,
                              hipStream_t stream) {
    const float* x      = (const float*)d_in[0];
    const float* qkv_w  = (const float*)d_in[1];
    const float* proj_w = (const float*)d_in[2];
    const float* proj_b = (const float*)d_in[3];
    float* out = (float*)d_out;

    char* ws = (char*)d_ws;
    bf16* xT    = (bf16*)(ws);                    // 4,194,304 B
    bf16* wqkv  = (bf16*)(ws + 4194304);          //   393,216 B
    bf16* Wp    = (bf16*)(ws + 4587520);          //   131,072 B (packed wproj)
    bf16* Qb    = (bf16*)(ws + 4718592);          // 4,194,304 B
    bf16* Kp    = (bf16*)(ws + 8912896);          // 4,194,304 B (fragment-packed)
    bf16* Vp    = (bf16*)(ws + 13107200);         // 4,194,304 B (fragment-packed)
    bf16* attP  = (bf16*)(ws + 17301504);         // 4,194,304 B (fragment-packed)

    prep_kernel<<<1536, 256, 0, stream>>>(x, qkv_w, proj_w, xT, wqkv, Wp);
    qkv_gemm_kernel<<<dim3(32, 6, 2), 256, 0, stream>>>(xT, wqkv, Qb, Kp, Vp);
    attn_kernel<<<1024, 512, 0, stream>>>(Qb, Kp, Vp, attP);
    proj_gemm_kernel<<<512, 256, 0, stream>>>(attP, Wp, proj_b, out);
}